// Round 1
// baseline (66.924 us; speedup 1.0000x reference)
//
#include <hip/hip_runtime.h>

// SpikeKernelLoss: loss = 0.5 * sum((outputs - psp(target))^2)
// psp: syn[t] = syn[t-1]*0.8 + target[t]; psp[t] = syn[t]/5
// Shapes: [128, 2048, 100] f32. Scan axis (T=100) is contiguous -> one
// thread per row, 25 float4 loads per input per row.

constexpr int T_LEN = 100;
constexpr int NF4   = T_LEN / 4;  // 25

__global__ __launch_bounds__(256) void spike_loss_main(
    const float* __restrict__ outs, const float* __restrict__ tgt,
    float* __restrict__ block_sums, int nrows)
{
    int row = blockIdx.x * blockDim.x + threadIdx.x;
    float acc = 0.0f;
    if (row < nrows) {
        const float4* tp = reinterpret_cast<const float4*>(tgt)  + (size_t)row * NF4;
        const float4* op = reinterpret_cast<const float4*>(outs) + (size_t)row * NF4;
        const float decay   = 0.8f;   // 1 - 1/tau
        const float inv_tau = 0.2f;   // 1/tau
        float syn = 0.0f;
        #pragma unroll
        for (int i = 0; i < NF4; ++i) {
            float4 tv = tp[i];
            float4 ov = op[i];
            float d;
            syn = fmaf(syn, decay, tv.x); d = fmaf(syn, -inv_tau, ov.x); acc = fmaf(d, d, acc);
            syn = fmaf(syn, decay, tv.y); d = fmaf(syn, -inv_tau, ov.y); acc = fmaf(d, d, acc);
            syn = fmaf(syn, decay, tv.z); d = fmaf(syn, -inv_tau, ov.z); acc = fmaf(d, d, acc);
            syn = fmaf(syn, decay, tv.w); d = fmaf(syn, -inv_tau, ov.w); acc = fmaf(d, d, acc);
        }
    }
    // wave = 64 lanes on gfx950
    #pragma unroll
    for (int off = 32; off > 0; off >>= 1) acc += __shfl_down(acc, off, 64);
    __shared__ float wsum[4];
    int lane = threadIdx.x & 63;
    int wid  = threadIdx.x >> 6;
    if (lane == 0) wsum[wid] = acc;
    __syncthreads();
    if (threadIdx.x == 0) {
        block_sums[blockIdx.x] = wsum[0] + wsum[1] + wsum[2] + wsum[3];
    }
}

__global__ __launch_bounds__(256) void spike_loss_reduce(
    const float* __restrict__ block_sums, float* __restrict__ out, int n)
{
    float acc = 0.0f;
    for (int i = threadIdx.x; i < n; i += 256) acc += block_sums[i];
    #pragma unroll
    for (int off = 32; off > 0; off >>= 1) acc += __shfl_down(acc, off, 64);
    __shared__ float wsum[4];
    int lane = threadIdx.x & 63;
    int wid  = threadIdx.x >> 6;
    if (lane == 0) wsum[wid] = acc;
    __syncthreads();
    if (threadIdx.x == 0) {
        out[0] = 0.5f * (wsum[0] + wsum[1] + wsum[2] + wsum[3]);
    }
}

extern "C" void kernel_launch(void* const* d_in, const int* in_sizes, int n_in,
                              void* d_out, int out_size, void* d_ws, size_t ws_size,
                              hipStream_t stream) {
    const float* outs = (const float*)d_in[0];   // outputs [128,2048,100]
    const float* tgt  = (const float*)d_in[1];   // target  [128,2048,100]
    float* out   = (float*)d_out;                // scalar loss
    float* bsums = (float*)d_ws;                 // per-block partials

    int nrows  = in_sizes[0] / T_LEN;            // 262144
    int blocks = (nrows + 255) / 256;            // 1024

    spike_loss_main<<<blocks, 256, 0, stream>>>(outs, tgt, bsums, nrows);
    spike_loss_reduce<<<1, 256, 0, stream>>>(bsums, out, blocks);
}

// Round 2
// 65.869 us; speedup vs baseline: 1.0160x; 1.0160x over previous
//
#include <hip/hip_runtime.h>

// SpikeKernelLoss: loss = 0.5 * sum((outputs - psp(target))^2)
// psp: syn[t] = syn[t-1]*0.8 + target[t]; psp[t] = syn[t]/5
// [128, 2048, 100] f32, scan axis contiguous. One thread per row.
// R1 fix: register double-buffered chunk prefetch to raise MLP
// (R0 had VGPR=32, ~1-2 loads in flight, 17% HBM BW, latency-bound).

constexpr int T_LEN = 100;
constexpr int NF4   = T_LEN / 4;  // 25 float4 per stream per row
constexpr int CH    = 5;          // float4 per chunk
constexpr int NCHUNK = NF4 / CH;  // 5 chunks

__global__ __launch_bounds__(256) void spike_loss_main(
    const float* __restrict__ outs, const float* __restrict__ tgt,
    float* __restrict__ block_sums, int nrows)
{
    int row = blockIdx.x * blockDim.x + threadIdx.x;
    float acc = 0.0f;
    if (row < nrows) {
        const float4* tp = reinterpret_cast<const float4*>(tgt)  + (size_t)row * NF4;
        const float4* op = reinterpret_cast<const float4*>(outs) + (size_t)row * NF4;
        const float decay   = 0.8f;   // 1 - 1/tau
        const float inv_tau = 0.2f;   // 1/tau

        float4 tc[CH], oc[CH];
        #pragma unroll
        for (int i = 0; i < CH; ++i) { tc[i] = tp[i]; oc[i] = op[i]; }

        float syn = 0.0f;
        #pragma unroll
        for (int c = 0; c < NCHUNK; ++c) {
            float4 tn[CH], on[CH];
            if (c + 1 < NCHUNK) {
                // prefetch next chunk (10 loads in flight while computing)
                #pragma unroll
                for (int i = 0; i < CH; ++i) {
                    tn[i] = tp[(c + 1) * CH + i];
                    on[i] = op[(c + 1) * CH + i];
                }
            }
            #pragma unroll
            for (int i = 0; i < CH; ++i) {
                float4 tv = tc[i], ov = oc[i];
                float d;
                syn = fmaf(syn, decay, tv.x); d = fmaf(syn, -inv_tau, ov.x); acc = fmaf(d, d, acc);
                syn = fmaf(syn, decay, tv.y); d = fmaf(syn, -inv_tau, ov.y); acc = fmaf(d, d, acc);
                syn = fmaf(syn, decay, tv.z); d = fmaf(syn, -inv_tau, ov.z); acc = fmaf(d, d, acc);
                syn = fmaf(syn, decay, tv.w); d = fmaf(syn, -inv_tau, ov.w); acc = fmaf(d, d, acc);
            }
            if (c + 1 < NCHUNK) {
                #pragma unroll
                for (int i = 0; i < CH; ++i) { tc[i] = tn[i]; oc[i] = on[i]; }
            }
        }
    }
    // wave = 64 lanes on gfx950
    #pragma unroll
    for (int off = 32; off > 0; off >>= 1) acc += __shfl_down(acc, off, 64);
    __shared__ float wsum[4];
    int lane = threadIdx.x & 63;
    int wid  = threadIdx.x >> 6;
    if (lane == 0) wsum[wid] = acc;
    __syncthreads();
    if (threadIdx.x == 0) {
        block_sums[blockIdx.x] = wsum[0] + wsum[1] + wsum[2] + wsum[3];
    }
}

__global__ __launch_bounds__(256) void spike_loss_reduce(
    const float* __restrict__ block_sums, float* __restrict__ out, int n)
{
    float acc = 0.0f;
    for (int i = threadIdx.x; i < n; i += 256) acc += block_sums[i];
    #pragma unroll
    for (int off = 32; off > 0; off >>= 1) acc += __shfl_down(acc, off, 64);
    __shared__ float wsum[4];
    int lane = threadIdx.x & 63;
    int wid  = threadIdx.x >> 6;
    if (lane == 0) wsum[wid] = acc;
    __syncthreads();
    if (threadIdx.x == 0) {
        out[0] = 0.5f * (wsum[0] + wsum[1] + wsum[2] + wsum[3]);
    }
}

extern "C" void kernel_launch(void* const* d_in, const int* in_sizes, int n_in,
                              void* d_out, int out_size, void* d_ws, size_t ws_size,
                              hipStream_t stream) {
    const float* outs = (const float*)d_in[0];   // outputs [128,2048,100]
    const float* tgt  = (const float*)d_in[1];   // target  [128,2048,100]
    float* out   = (float*)d_out;                // scalar loss
    float* bsums = (float*)d_ws;                 // per-block partials

    int nrows  = in_sizes[0] / T_LEN;            // 262144
    int blocks = (nrows + 255) / 256;            // 1024

    spike_loss_main<<<blocks, 256, 0, stream>>>(outs, tgt, bsums, nrows);
    spike_loss_reduce<<<1, 256, 0, stream>>>(bsums, out, blocks);
}

// Round 5
// 41.658 us; speedup vs baseline: 1.6065x; 1.5812x over previous
//
#include <hip/hip_runtime.h>

// SpikeKernelLoss: loss = 0.5 * sum((outputs - psp(target))^2)
// psp: syn[t] = syn[t-1]*0.8 + target[t]; psp[t] = syn[t]/5
// [128, 2048, 100] f32, scan axis contiguous. One thread per row.
//
// R2 diagnosis: VGPR=32 both rounds -> compiler sinks loads next to uses,
// ~0.25 loads in flight per wave, latency-bound at 17% HBM BW. L3-resident
// replays show SAME dur -> latency, not bandwidth.
// R2 fix: load ALL 50 float4 up front, pin with sched_barrier(0) so the
// scheduler cannot sink them; launch_bounds(256,1) permits ~210 VGPRs.
// (R3/R4 = identical resubmits; bench container was unresponsive.)

constexpr int T_LEN = 100;
constexpr int NF4   = T_LEN / 4;  // 25 float4 per stream per row

typedef __attribute__((ext_vector_type(4))) float f32x4;

__global__ __launch_bounds__(256, 1) void spike_loss_main(
    const float* __restrict__ outs, const float* __restrict__ tgt,
    float* __restrict__ block_sums, int nrows)
{
    int row = blockIdx.x * blockDim.x + threadIdx.x;
    float acc = 0.0f;
    if (row < nrows) {
        const f32x4* tp = reinterpret_cast<const f32x4*>(tgt)  + (size_t)row * NF4;
        const f32x4* op = reinterpret_cast<const f32x4*>(outs) + (size_t)row * NF4;
        const float decay   = 0.8f;   // 1 - 1/tau
        const float inv_tau = 0.2f;   // 1/tau

        // Issue ALL loads first (interleaved so first-consumed returns first).
        // Fully unrolled -> static indices -> stays in registers (rule #20).
        f32x4 tv[NF4], ov[NF4];
        #pragma unroll
        for (int i = 0; i < NF4; ++i) {
            tv[i] = tp[i];
            ov[i] = op[i];
        }
        // Hard scheduling fence: nothing moves across. Loads stay issued
        // above; ~200 VGPRs live here -> 2 waves/SIMD, 50 loads in flight.
        __builtin_amdgcn_sched_barrier(0);

        float syn = 0.0f;
        #pragma unroll
        for (int i = 0; i < NF4; ++i) {
            float d;
            syn = fmaf(syn, decay, tv[i].x); d = fmaf(syn, -inv_tau, ov[i].x); acc = fmaf(d, d, acc);
            syn = fmaf(syn, decay, tv[i].y); d = fmaf(syn, -inv_tau, ov[i].y); acc = fmaf(d, d, acc);
            syn = fmaf(syn, decay, tv[i].z); d = fmaf(syn, -inv_tau, ov[i].z); acc = fmaf(d, d, acc);
            syn = fmaf(syn, decay, tv[i].w); d = fmaf(syn, -inv_tau, ov[i].w); acc = fmaf(d, d, acc);
        }
    }
    // wave = 64 lanes on gfx950
    #pragma unroll
    for (int off = 32; off > 0; off >>= 1) acc += __shfl_down(acc, off, 64);
    __shared__ float wsum[4];
    int lane = threadIdx.x & 63;
    int wid  = threadIdx.x >> 6;
    if (lane == 0) wsum[wid] = acc;
    __syncthreads();
    if (threadIdx.x == 0) {
        block_sums[blockIdx.x] = wsum[0] + wsum[1] + wsum[2] + wsum[3];
    }
}

__global__ __launch_bounds__(256) void spike_loss_reduce(
    const float* __restrict__ block_sums, float* __restrict__ out, int n)
{
    float acc = 0.0f;
    for (int i = threadIdx.x; i < n; i += 256) acc += block_sums[i];
    #pragma unroll
    for (int off = 32; off > 0; off >>= 1) acc += __shfl_down(acc, off, 64);
    __shared__ float wsum[4];
    int lane = threadIdx.x & 63;
    int wid  = threadIdx.x >> 6;
    if (lane == 0) wsum[wid] = acc;
    __syncthreads();
    if (threadIdx.x == 0) {
        out[0] = 0.5f * (wsum[0] + wsum[1] + wsum[2] + wsum[3]);
    }
}

extern "C" void kernel_launch(void* const* d_in, const int* in_sizes, int n_in,
                              void* d_out, int out_size, void* d_ws, size_t ws_size,
                              hipStream_t stream) {
    const float* outs = (const float*)d_in[0];   // outputs [128,2048,100]
    const float* tgt  = (const float*)d_in[1];   // target  [128,2048,100]
    float* out   = (float*)d_out;                // scalar loss
    float* bsums = (float*)d_ws;                 // per-block partials

    int nrows  = in_sizes[0] / T_LEN;            // 262144
    int blocks = (nrows + 255) / 256;            // 1024

    spike_loss_main<<<blocks, 256, 0, stream>>>(outs, tgt, bsums, nrows);
    spike_loss_reduce<<<1, 256, 0, stream>>>(bsums, out, blocks);
}

// Round 6
// 39.886 us; speedup vs baseline: 1.6779x; 1.0444x over previous
//
#include <hip/hip_runtime.h>

// SpikeKernelLoss: loss = 0.5 * sum((outputs - psp(target))^2)
// psp: syn[t] = syn[t-1]*0.8 + target[t]; psp[t] = syn[t]/5
// [128, 2048, 100] f32.
//
// R6: the scan is LINEAR -> split each row into 4 segments (28/24/24/24
// steps, all 16B-aligned). Each thread scans its segment with syn0=0,
// accumulating A = sum(d_l^2), B = sum(d_l*w_t), w_t = 0.2*0.8^(t+1).
// True contribution = A - 2*s*B + s^2*C (C compile-time), with carry s
// reconstructed EXACTLY from partner lanes' local finals via __shfl(.,.,4)
// and decay powers. 4x waves (16384) attacks the R5 latency/TLP limit.

constexpr int NF4 = 25;            // float4 per stream per row (T=100)

typedef __attribute__((ext_vector_type(4))) float f32x4;

constexpr double DECAY_D = 0.8;
constexpr float pw(double b, int n) {
    double r = 1.0; for (int i = 0; i < n; ++i) r *= b; return (float)r;
}
constexpr float csum(int L) {            // sum_{t=0..L-1} (0.2*0.8^(t+1))^2
    double c = 0.0, w = 0.16;
    for (int t = 0; t < L; ++t) { c += w * w; w *= DECAY_D; }
    return (float)c;
}

__global__ __launch_bounds__(256, 4) void spike_loss_main(
    const float* __restrict__ outs, const float* __restrict__ tgt,
    float* __restrict__ block_sums, int nthreads)
{
    int tid = blockIdx.x * blockDim.x + threadIdx.x;
    float contrib = 0.0f;
    float syn = 0.0f;
    float A = 0.0f, B = 0.0f;
    int seg = tid & 3;
    if (tid < nthreads) {
        int row = tid >> 2;
        int off = (seg == 0) ? 0 : (7 + (seg - 1) * 6);   // f4 offsets 0,7,13,19
        int nf4 = (seg == 0) ? 7 : 6;                     // 28 / 24 elements
        const f32x4* tp = reinterpret_cast<const f32x4*>(tgt)  + (size_t)row * NF4 + off;
        const f32x4* op = reinterpret_cast<const f32x4*>(outs) + (size_t)row * NF4 + off;

        // Issue all segment loads up front; pin with sched_barrier so the
        // scheduler can't sink them (R5: this raised VGPR 32->104, -38% dur).
        f32x4 tv[7], ov[7];
        #pragma unroll
        for (int i = 0; i < 7; ++i) {
            if (i < nf4) { tv[i] = tp[i]; ov[i] = op[i]; }
        }
        __builtin_amdgcn_sched_barrier(0);

        const float decay = 0.8f, inv_tau = 0.2f;
        float w = 0.16f;                                   // 0.2 * 0.8^1
        #pragma unroll
        for (int i = 0; i < 7; ++i) {
            if (i < nf4) {
                float d;
                syn = fmaf(syn, decay, tv[i].x); d = fmaf(syn, -inv_tau, ov[i].x); A = fmaf(d, d, A); B = fmaf(d, w, B); w *= decay;
                syn = fmaf(syn, decay, tv[i].y); d = fmaf(syn, -inv_tau, ov[i].y); A = fmaf(d, d, A); B = fmaf(d, w, B); w *= decay;
                syn = fmaf(syn, decay, tv[i].z); d = fmaf(syn, -inv_tau, ov[i].z); A = fmaf(d, d, A); B = fmaf(d, w, B); w *= decay;
                syn = fmaf(syn, decay, tv[i].w); d = fmaf(syn, -inv_tau, ov[i].w); A = fmaf(d, d, A); B = fmaf(d, w, B); w *= decay;
            }
        }
    }
    // Exact carry reconstruction across the 4 segment lanes of this row.
    float l0 = __shfl(syn, 0, 4);
    float l1 = __shfl(syn, 1, 4);
    float l2 = __shfl(syn, 2, 4);
    constexpr float K24 = pw(DECAY_D, 24);    // 0.8^24
    float s = 0.0f;
    if      (seg == 1) s = l0;
    else if (seg == 2) s = fmaf(l0, K24, l1);
    else if (seg == 3) s = fmaf(fmaf(l0, K24, l1), K24, l2);
    constexpr float C28 = csum(28);
    constexpr float C24 = csum(24);
    float C = (seg == 0) ? C28 : C24;
    contrib = fmaf(s * s, C, fmaf(-2.0f * s, B, A));

    // wave (64-lane) reduction, then cross-wave via LDS
    #pragma unroll
    for (int offr = 32; offr > 0; offr >>= 1) contrib += __shfl_down(contrib, offr, 64);
    __shared__ float wsum[4];
    int lane = threadIdx.x & 63;
    int wid  = threadIdx.x >> 6;
    if (lane == 0) wsum[wid] = contrib;
    __syncthreads();
    if (threadIdx.x == 0) {
        block_sums[blockIdx.x] = wsum[0] + wsum[1] + wsum[2] + wsum[3];
    }
}

__global__ __launch_bounds__(256) void spike_loss_reduce(
    const float* __restrict__ block_sums, float* __restrict__ out, int n)
{
    float acc = 0.0f;
    for (int i = threadIdx.x; i < n; i += 256) acc += block_sums[i];
    #pragma unroll
    for (int off = 32; off > 0; off >>= 1) acc += __shfl_down(acc, off, 64);
    __shared__ float wsum[4];
    int lane = threadIdx.x & 63;
    int wid  = threadIdx.x >> 6;
    if (lane == 0) wsum[wid] = acc;
    __syncthreads();
    if (threadIdx.x == 0) {
        out[0] = 0.5f * (wsum[0] + wsum[1] + wsum[2] + wsum[3]);
    }
}

extern "C" void kernel_launch(void* const* d_in, const int* in_sizes, int n_in,
                              void* d_out, int out_size, void* d_ws, size_t ws_size,
                              hipStream_t stream) {
    const float* outs = (const float*)d_in[0];   // outputs [128,2048,100]
    const float* tgt  = (const float*)d_in[1];   // target  [128,2048,100]
    float* out   = (float*)d_out;                // scalar loss
    float* bsums = (float*)d_ws;                 // per-block partials

    int nrows    = in_sizes[0] / 100;            // 262144
    int nthreads = nrows * 4;                    // 4 segment-threads per row
    int blocks   = (nthreads + 255) / 256;       // 4096

    spike_loss_main<<<blocks, 256, 0, stream>>>(outs, tgt, bsums, nthreads);
    spike_loss_reduce<<<1, 256, 0, stream>>>(bsums, out, blocks);
}